// Round 5
// baseline (377.990 us; speedup 1.0000x reference)
//
#include <hip/hip_runtime.h>
#include <stdint.h>

#define FEAT   128
#define GR     64
#define LDA    136   // 128 + 8 bf16 pad
#define NBUCK  256
#define BSHIFT 9     // 512 nodes per bucket

typedef __attribute__((ext_vector_type(8))) short bf8_t;
typedef __attribute__((ext_vector_type(4))) float f4_t;

__device__ inline float bf2f(ushort h){
    union { uint u; float f; } v; v.u = ((uint)h) << 16; return v.f;
}
__device__ inline float bf2f_lo(uint u){   // low bf16 of packed pair -> float
    union { uint u; float f; } v; v.u = u << 16; return v.f;
}
__device__ inline float bf2f_hi(uint u){   // high bf16 of packed pair -> float
    union { uint u; float f; } v; v.u = u & 0xffff0000u; return v.f;
}
__device__ inline ushort f2bf(float f){
    union { float f; uint u; } v; v.f = f;
    uint r = (v.u + 0x7FFFu + ((v.u >> 16) & 1u)) >> 16;   // RNE
    return (ushort)r;
}

// ========== fused prep: cast features + cast weights + bucket histogram ==========
__global__ __launch_bounds__(256) void k_prep(
    const float* __restrict__ x, ushort* __restrict__ xb, int n4, int nbCast,
    const float* __restrict__ a0, const float* __restrict__ a1,
    const float* __restrict__ a2, const float* __restrict__ a3,
    ushort* __restrict__ o0, ushort* __restrict__ o1,
    ushort* __restrict__ o2, ushort* __restrict__ o3,
    const int* __restrict__ dst, int* __restrict__ bcnt, int E)
{
    int bid = blockIdx.x;
    if (bid < nbCast){                       // ---- feature cast ----
        int i = bid * 256 + threadIdx.x;
        if (i >= n4) return;
        float4 v = ((const float4*)x)[i];
        ushort4 o; o.x = f2bf(v.x); o.y = f2bf(v.y); o.z = f2bf(v.z); o.w = f2bf(v.w);
        ((ushort4*)xb)[i] = o;
        return;
    }
    if (bid < nbCast + 64){                  // ---- weight cast (4 x 128x128) ----
        int i = (bid - nbCast) * 256 + threadIdx.x;   // 0..16383 float4s
        int sel = i >> 12, j = i & 4095;
        const float* s = sel == 0 ? a0 : sel == 1 ? a1 : sel == 2 ? a2 : a3;
        ushort*      d = sel == 0 ? o0 : sel == 1 ? o1 : sel == 2 ? o2 : o3;
        float4 v = ((const float4*)s)[j];
        ushort4 o; o.x = f2bf(v.x); o.y = f2bf(v.y); o.z = f2bf(v.z); o.w = f2bf(v.w);
        ((ushort4*)d)[j] = o;
        return;
    }
    // ---- bucket histogram ----
    __shared__ int h[NBUCK];
    h[threadIdx.x] = 0;
    __syncthreads();
    int base = (bid - nbCast - 64) * 4096 + threadIdx.x;
    #pragma unroll
    for (int k = 0; k < 16; k++){
        int e = base + k * 256;
        if (e < E) atomicAdd(&h[dst[e] >> BSHIFT], 1);
    }
    __syncthreads();
    int c = h[threadIdx.x];
    if (c) atomicAdd(&bcnt[threadIdx.x], c);
}

// ================= CSR build via bucket counting-sort =================
// Also zeroes pooled accumulator + last-block counter (saves a memset launch).
__global__ void k_bscan(const int* __restrict__ bcnt, int* __restrict__ bbase,
                        int* __restrict__ bpos, int* __restrict__ rowp,
                        int* __restrict__ csr, float* __restrict__ pooled,
                        int* __restrict__ ctr, int E, int M){
    __shared__ int sd[NBUCK];
    int t = threadIdx.x;
    #pragma unroll
    for (int k = 0; k < 32; k++) pooled[t * 32 + k] = 0.f;   // 256*32 = 8192
    if (t == 0) *ctr = 0;
    int v = bcnt[t];
    sd[t] = v; __syncthreads();
    for (int off = 1; off < NBUCK; off <<= 1){
        int x = (t >= off) ? sd[t - off] : 0;
        __syncthreads();
        sd[t] += x;
        __syncthreads();
    }
    int ex = sd[t] - v;
    bbase[t] = ex;
    bpos[t]  = ex;
    if (t < 8) csr[E + t] = 0;                 // zero the read-ahead pad
    if (t == NBUCK - 1){ bbase[NBUCK] = sd[t]; rowp[M] = E; }
}

__global__ __launch_bounds__(256) void k_bucket(const int* __restrict__ src,
                                                const int* __restrict__ dst,
                                                int* __restrict__ bpos,
                                                int2* __restrict__ bp, int E){
    __shared__ int h[NBUCK];
    __shared__ int bb[NBUCK];
    int t = threadIdx.x;
    h[t] = 0;
    __syncthreads();
    int base = blockIdx.x * 4096 + t;
    int bk[16], sv[16], dv[16];
    #pragma unroll
    for (int k = 0; k < 16; k++){
        int e = base + k * 256;
        if (e < E){
            dv[k] = dst[e]; sv[k] = src[e];
            bk[k] = dv[k] >> BSHIFT;
            atomicAdd(&h[bk[k]], 1);
        } else bk[k] = -1;
    }
    __syncthreads();
    int c = h[t];
    bb[t] = c ? atomicAdd(&bpos[t], c) : 0;
    __syncthreads();
    h[t] = 0;
    __syncthreads();
    #pragma unroll
    for (int k = 0; k < 16; k++){
        if (bk[k] >= 0){
            int r = atomicAdd(&h[bk[k]], 1);
            bp[bb[bk[k]] + r] = make_int2(sv[k], dv[k]);
        }
    }
}

__global__ __launch_bounds__(512) void k_csr(const int2* __restrict__ bp,
                                             const int* __restrict__ bbase,
                                             int* __restrict__ rowp,
                                             int* __restrict__ csr, int M){
    __shared__ int cnt[512];
    __shared__ int sd[512];
    int b = blockIdx.x, t = threadIdx.x;
    int nbase = b << BSHIFT;
    int nnodes = min(512, M - nbase);
    int e0 = bbase[b], e1 = bbase[b + 1];
    cnt[t] = 0;
    __syncthreads();
    for (int e = e0 + t; e < e1; e += 512)
        atomicAdd(&cnt[bp[e].y - nbase], 1);
    __syncthreads();
    int v = cnt[t];
    sd[t] = v; __syncthreads();
    for (int off = 1; off < 512; off <<= 1){
        int x = (t >= off) ? sd[t - off] : 0;
        __syncthreads();
        sd[t] += x;
        __syncthreads();
    }
    int ex = sd[t] - v;
    if (t < nnodes) rowp[nbase + t] = e0 + ex;
    cnt[t] = ex;     // running cursor
    __syncthreads();
    for (int e = e0 + t; e < e1; e += 512){
        int2 pr = bp[e];
        int r = atomicAdd(&cnt[pr.y - nbase], 1);
        csr[e0 + r] = pr.x;
    }
}

// ---------------- mean aggregation: 16 lanes/node, 4 nodes/wave, 8-deep ----------------
// At the per-CU VMEM service ceiling (~10 B/cyc/CU) — structural floor for bf16.
#define ACCA(vv)                                   \
    a0 += bf2f_lo((vv).x); a1 += bf2f_hi((vv).x);  \
    a2 += bf2f_lo((vv).y); a3 += bf2f_hi((vv).y);  \
    a4 += bf2f_lo((vv).z); a5 += bf2f_hi((vv).z);  \
    a6 += bf2f_lo((vv).w); a7 += bf2f_hi((vv).w);
#define ACCB(vv)                                   \
    b0 += bf2f_lo((vv).x); b1 += bf2f_hi((vv).x);  \
    b2 += bf2f_lo((vv).y); b3 += bf2f_hi((vv).y);  \
    b4 += bf2f_lo((vv).z); b5 += bf2f_hi((vv).z);  \
    b6 += bf2f_lo((vv).w); b7 += bf2f_hi((vv).w);

__global__ __launch_bounds__(256) void k_agg(const ushort* __restrict__ srcf,
                                             const int* __restrict__ rowp,
                                             const int* __restrict__ csr,
                                             ushort* __restrict__ aggb, int M){
    int node = blockIdx.x * 16 + (threadIdx.x >> 4);
    int l    = threadIdx.x & 15;
    if (node >= M) return;
    int s = rowp[node], e = rowp[node + 1];
    const char* base = (const char*)srcf + (uint)l * 16u;   // this lane's 8 feats
    float a0 = 0.f, a1 = 0.f, a2 = 0.f, a3 = 0.f;
    float a4 = 0.f, a5 = 0.f, a6 = 0.f, a7 = 0.f;
    float b0 = 0.f, b1 = 0.f, b2 = 0.f, b3 = 0.f;
    float b4 = 0.f, b5 = 0.f, b6 = 0.f, b7 = 0.f;
    int i = s;
    for (; i + 8 <= e; i += 8){
        int idx[8];
        __builtin_memcpy(idx, csr + i, 32);        // two group-uniform dwordx4
        uint4 v0 = *(const uint4*)(base + ((uint)idx[0] << 8));
        uint4 v1 = *(const uint4*)(base + ((uint)idx[1] << 8));
        uint4 v2 = *(const uint4*)(base + ((uint)idx[2] << 8));
        uint4 v3 = *(const uint4*)(base + ((uint)idx[3] << 8));
        uint4 v4 = *(const uint4*)(base + ((uint)idx[4] << 8));
        uint4 v5 = *(const uint4*)(base + ((uint)idx[5] << 8));
        uint4 v6 = *(const uint4*)(base + ((uint)idx[6] << 8));
        uint4 v7 = *(const uint4*)(base + ((uint)idx[7] << 8));
        ACCA(v0); ACCA(v1); ACCA(v2); ACCA(v3);
        ACCB(v4); ACCB(v5); ACCB(v6); ACCB(v7);
    }
    if (i + 4 <= e){
        int idx[4];
        __builtin_memcpy(idx, csr + i, 16);
        uint4 v0 = *(const uint4*)(base + ((uint)idx[0] << 8));
        uint4 v1 = *(const uint4*)(base + ((uint)idx[1] << 8));
        uint4 v2 = *(const uint4*)(base + ((uint)idx[2] << 8));
        uint4 v3 = *(const uint4*)(base + ((uint)idx[3] << 8));
        ACCA(v0); ACCA(v1); ACCB(v2); ACCB(v3);
        i += 4;
    }
    for (; i < e; i++){                            // <=3 tail edges
        uint4 v = *(const uint4*)(base + ((uint)csr[i] << 8));
        ACCA(v);
    }
    float inv = (e > s) ? 1.0f / (float)(e - s) : 0.f;  // count clamped to 1
    uint4 o;
    o.x = ((uint)f2bf((a1 + b1) * inv) << 16) | (uint)f2bf((a0 + b0) * inv);
    o.y = ((uint)f2bf((a3 + b3) * inv) << 16) | (uint)f2bf((a2 + b2) * inv);
    o.z = ((uint)f2bf((a5 + b5) * inv) << 16) | (uint)f2bf((a4 + b4) * inv);
    o.w = ((uint)f2bf((a7 + b7) * inv) << 16) | (uint)f2bf((a6 + b6) * inv);
    *(uint4*)(aggb + (size_t)node * FEAT + l * 8) = o;
}

// ---------------- fused SAGE linear: H = relu(AGG@Wl^T + b + A@Wr^T) ----------------
// 128-row tiles, 512 threads (8 waves x 16 rows). W staged in LDS; A-fragments
// direct from global. mode 0: store H (layer 1). mode 1 (layer 2): fuse graph
// mean-pooling (wave quad-reduce + 1 atomic/col/wave) and, in the last block,
// the final linear — h2 never touches HBM.
__global__ __launch_bounds__(512) void k_gemm(
    const ushort* __restrict__ Aagg, const ushort* __restrict__ Aself,
    const ushort* __restrict__ Wl, const ushort* __restrict__ Wr,
    const float* __restrict__ bias, ushort* __restrict__ Hout, int M, int mode,
    float* __restrict__ pooled, const int* __restrict__ batch, int* __restrict__ ctr,
    const float* __restrict__ embed, const float* __restrict__ Wlin,
    const float* __restrict__ blin, float* __restrict__ out)
{
    __shared__ ushort Bs[128 * LDA];
    const int tid  = threadIdx.x;
    const int lane = tid & 63;
    const int wave = tid >> 6;          // 0..7
    const int l15  = lane & 15;
    const int quad = lane >> 4;
    const int m0   = blockIdx.x * 128;

    int arow = m0 + wave * 16 + l15;
    if (arow >= M) arow = M - 1;        // clamped; junk only corrupts masked rows
    const ushort* ap0 = Aagg  + (size_t)arow * FEAT + quad * 8;
    const ushort* ap1 = Aself + (size_t)arow * FEAT + quad * 8;

    f4_t acc[8];
    #pragma unroll
    for (int i = 0; i < 8; i++) acc[i] = (f4_t){0.f, 0.f, 0.f, 0.f};

    #pragma unroll
    for (int pass = 0; pass < 2; pass++){
        const ushort* Ap = pass ? ap1 : ap0;
        const ushort* Wp = pass ? Wr  : Wl;
        #pragma unroll
        for (int it = 0; it < 4; it++){          // 2048 int4 / 512 thr
            int idx = (it * 512 + tid) * 8;
            int r = idx >> 7, c = idx & 127;
            *(int4*)(&Bs[r * LDA + c]) = *(const int4*)(Wp + idx);
        }
        bf8_t ga0 = *(const bf8_t*)(Ap);
        bf8_t ga1 = *(const bf8_t*)(Ap + 32);
        bf8_t ga2 = *(const bf8_t*)(Ap + 64);
        bf8_t ga3 = *(const bf8_t*)(Ap + 96);
        __syncthreads();
        const ushort* brow = &Bs[l15 * LDA + quad * 8];
        #pragma unroll
        for (int nt = 0; nt < 8; nt++){
            const ushort* b = brow + nt * 16 * LDA;
            acc[nt] = __builtin_amdgcn_mfma_f32_16x16x32_bf16(ga0, *(const bf8_t*)(b),      acc[nt], 0, 0, 0);
            acc[nt] = __builtin_amdgcn_mfma_f32_16x16x32_bf16(ga1, *(const bf8_t*)(b + 32), acc[nt], 0, 0, 0);
            acc[nt] = __builtin_amdgcn_mfma_f32_16x16x32_bf16(ga2, *(const bf8_t*)(b + 64), acc[nt], 0, 0, 0);
            acc[nt] = __builtin_amdgcn_mfma_f32_16x16x32_bf16(ga3, *(const bf8_t*)(b + 96), acc[nt], 0, 0, 0);
        }
        __syncthreads();
    }

    if (mode == 0){
        // ---- layer-1 epilogue: bias + relu -> bf16 store ----
        #pragma unroll
        for (int nt = 0; nt < 8; nt++){
            int col = nt * 16 + l15;
            float bcol = bias[col];
            #pragma unroll
            for (int reg = 0; reg < 4; reg++){
                int gm = m0 + wave * 16 + quad * 4 + reg;
                if (gm < M){
                    float v = acc[nt][reg] + bcol;
                    v = v > 0.f ? v : 0.f;
                    Hout[(size_t)gm * FEAT + col] = f2bf(v);
                }
            }
        }
        return;
    }

    // ---- layer-2 epilogue: fused graph mean-pool (sorted batch) ----
    {
        int row0 = m0 + wave * 16 + quad * 4;          // this lane's 4 rows
        bool wfull = (m0 + wave * 16 + 16 <= M);       // wave's 16-row window valid
        if (wfull){
            int4 gq = *(const int4*)(batch + row0);
            int g_lo = __shfl(gq.x, 0);                // row wave*16 + 0
            int g_hi = __shfl(gq.w, 48);               // row wave*16 + 15
            if (g_lo == g_hi){
                // fast path: whole window one graph -> quad-reduce, 1 atomic/col
                #pragma unroll
                for (int nt = 0; nt < 8; nt++){
                    float bcol = bias[nt * 16 + l15];
                    float v = 0.f;
                    #pragma unroll
                    for (int reg = 0; reg < 4; reg++){
                        float t = acc[nt][reg] + bcol;
                        v += t > 0.f ? t : 0.f;
                    }
                    v += __shfl_xor(v, 16);
                    v += __shfl_xor(v, 32);
                    if (lane < 16)
                        atomicAdd(&pooled[g_lo * FEAT + nt * 16 + l15], v);
                }
            } else {
                // window spans graphs: run-length per lane (same granularity as old k_pool)
                #pragma unroll
                for (int nt = 0; nt < 8; nt++){
                    int col = nt * 16 + l15;
                    float bcol = bias[col];
                    float s = 0.f; int g = gq.x;
                    #pragma unroll
                    for (int reg = 0; reg < 4; reg++){
                        int gn = reg == 0 ? gq.x : reg == 1 ? gq.y : reg == 2 ? gq.z : gq.w;
                        float t = acc[nt][reg] + bcol;
                        t = t > 0.f ? t : 0.f;
                        if (gn != g){ atomicAdd(&pooled[g * FEAT + col], s); s = 0.f; g = gn; }
                        s += t;
                    }
                    atomicAdd(&pooled[g * FEAT + col], s);
                }
            }
        } else if (row0 < M){
            // partial window: per-row guarded atomics (rare tail)
            #pragma unroll
            for (int nt = 0; nt < 8; nt++){
                int col = nt * 16 + l15;
                float bcol = bias[col];
                #pragma unroll
                for (int reg = 0; reg < 4; reg++){
                    int gm = row0 + reg;
                    if (gm < M){
                        float t = acc[nt][reg] + bcol;
                        t = t > 0.f ? t : 0.f;
                        atomicAdd(&pooled[batch[gm] * FEAT + col], t);
                    }
                }
            }
        }
    }

    // ---- last block finishes: final linear over [pooled/cnt | embed] ----
    __threadfence();
    __shared__ int slast;
    if (tid == 0) slast = atomicAdd(ctr, 1);
    __syncthreads();
    if (slast != (int)gridDim.x - 1) return;

    int t = tid;
    if (t >= GR * 8) return;
    int g = t >> 3, o = t & 7;
    int lo = 0, hi = M;
    while (lo < hi){ int mid = (lo + hi) >> 1; if (batch[mid] < g) lo = mid + 1; else hi = mid; }
    int s0 = lo;
    lo = s0; hi = M;
    while (lo < hi){ int mid = (lo + hi) >> 1; if (batch[mid] < g + 1) lo = mid + 1; else hi = mid; }
    int c = lo - s0;
    float inv = (c > 0) ? 1.0f / (float)c : 0.f;
    float accf = blin[o];
    const float* wr = Wlin + o * (FEAT + GR);
    for (int k = 0; k < FEAT; k++){
        float pv = __hip_atomic_load(&pooled[g * FEAT + k], __ATOMIC_RELAXED,
                                     __HIP_MEMORY_SCOPE_AGENT);
        accf += pv * inv * wr[k];
    }
    for (int k = 0; k < GR; k++) accf += embed[g * GR + k] * wr[FEAT + k];
    out[g * 8 + o] = accf;
}

extern "C" void kernel_launch(void* const* d_in, const int* in_sizes, int n_in,
                              void* d_out, int out_size, void* d_ws, size_t ws_size,
                              hipStream_t stream)
{
    const float* x     = (const float*)d_in[0];
    const int*   eidx  = (const int*)d_in[1];
    const int*   batch = (const int*)d_in[2];
    const float* embed = (const float*)d_in[3];
    const float* W1l   = (const float*)d_in[4];
    const float* b1l   = (const float*)d_in[5];
    const float* W1r   = (const float*)d_in[6];
    const float* W2l   = (const float*)d_in[7];
    const float* b2l   = (const float*)d_in[8];
    const float* W2r   = (const float*)d_in[9];
    const float* Wlin  = (const float*)d_in[10];
    const float* blin  = (const float*)d_in[11];
    float* out = (float*)d_out;

    const int M = in_sizes[0] / FEAT;   // 100000
    const int E = in_sizes[1] / 2;      // 800000
    const int* src = eidx;
    const int* dst = eidx + E;

    char* w = (char*)d_ws;
    size_t off = 0;
    auto alloc = [&](size_t sz){ void* p = w + off; off = (off + sz + 255) & ~(size_t)255; return p; };
    ushort* xb     = (ushort*)alloc((size_t)M * FEAT * 2);
    ushort* aggb   = (ushort*)alloc((size_t)M * FEAT * 2);
    ushort* h1b    = (ushort*)alloc((size_t)M * FEAT * 2);
    int*    rowp   = (int*)alloc((size_t)(M + 1) * 4);
    int*    csr    = (int*)alloc((size_t)(E + 8) * 4);   // +8 read-ahead pad
    int*    bcnt   = (int*)alloc(NBUCK * 4);
    int*    bbase  = (int*)alloc((NBUCK + 1) * 4);
    int*    bpos   = (int*)alloc(NBUCK * 4);
    float*  pooled = (float*)alloc((size_t)GR * FEAT * 4);
    int*    ctr    = (int*)alloc(256);
    ushort* w1lb   = (ushort*)alloc((size_t)FEAT * FEAT * 2);
    ushort* w1rb   = (ushort*)alloc((size_t)FEAT * FEAT * 2);
    ushort* w2lb   = (ushort*)alloc((size_t)FEAT * FEAT * 2);
    ushort* w2rb   = (ushort*)alloc((size_t)FEAT * FEAT * 2);
    int2*   bp     = (int2*)aggb;   // bucket-sorted pairs; dead before aggb first written

    hipMemsetAsync(bcnt, 0, NBUCK * 4, stream);

    const int n4     = M * FEAT / 4;
    const int nbCast = (n4 + 255) / 256;
    const int nb     = (M + 511) >> BSHIFT;     // buckets actually populated
    const int ebk    = (E + 4095) / 4096;       // edge-chunk blocks
    const int gemmb  = (M + 127) / 128;
    k_prep  <<<nbCast + 64 + ebk, 256, 0, stream>>>(x, xb, n4, nbCast,
                                                    W1l, W1r, W2l, W2r,
                                                    w1lb, w1rb, w2lb, w2rb,
                                                    dst, bcnt, E);
    k_bscan <<<1, NBUCK, 0, stream>>>(bcnt, bbase, bpos, rowp, csr, pooled, ctr, E, M);
    k_bucket<<<ebk, 256, 0, stream>>>(src, dst, bpos, bp, E);
    k_csr   <<<nb, 512, 0, stream>>>(bp, bbase, rowp, csr, M);
    k_agg   <<<(M + 15) / 16, 256, 0, stream>>>(xb, rowp, csr, aggb, M);
    k_gemm  <<<gemmb, 512, 0, stream>>>(aggb, xb, w1lb, w1rb, b1l, h1b, M, 0,
                                        nullptr, nullptr, nullptr, nullptr, nullptr, nullptr, nullptr);
    k_agg   <<<(M + 15) / 16, 256, 0, stream>>>(h1b, rowp, csr, aggb, M);
    k_gemm  <<<gemmb, 512, 0, stream>>>(aggb, h1b, w2lb, w2rb, b2l, nullptr, M, 1,
                                        pooled, batch, ctr, embed, Wlin, blin, out);
}

// Round 6
// 282.141 us; speedup vs baseline: 1.3397x; 1.3397x over previous
//
#include <hip/hip_runtime.h>
#include <stdint.h>

#define FEAT   128
#define GR     64
#define LDA    136   // 128 + 8 bf16 pad
#define NBUCK  256
#define BSHIFT 9     // 512 nodes per bucket

typedef __attribute__((ext_vector_type(8))) short bf8_t;
typedef __attribute__((ext_vector_type(4))) float f4_t;

__device__ inline float bf2f(ushort h){
    union { uint u; float f; } v; v.u = ((uint)h) << 16; return v.f;
}
__device__ inline float bf2f_lo(uint u){   // low bf16 of packed pair -> float
    union { uint u; float f; } v; v.u = u << 16; return v.f;
}
__device__ inline float bf2f_hi(uint u){   // high bf16 of packed pair -> float
    union { uint u; float f; } v; v.u = u & 0xffff0000u; return v.f;
}
__device__ inline ushort f2bf(float f){
    union { float f; uint u; } v; v.f = f;
    uint r = (v.u + 0x7FFFu + ((v.u >> 16) & 1u)) >> 16;   // RNE
    return (ushort)r;
}

// ========== fused prep: cast features + cast weights + bucket histogram ==========
__global__ __launch_bounds__(256) void k_prep(
    const float* __restrict__ x, ushort* __restrict__ xb, int n4, int nbCast,
    const float* __restrict__ a0, const float* __restrict__ a1,
    const float* __restrict__ a2, const float* __restrict__ a3,
    ushort* __restrict__ o0, ushort* __restrict__ o1,
    ushort* __restrict__ o2, ushort* __restrict__ o3,
    const int* __restrict__ dst, int* __restrict__ bcnt, int E)
{
    int bid = blockIdx.x;
    if (bid < nbCast){                       // ---- feature cast ----
        int i = bid * 256 + threadIdx.x;
        if (i >= n4) return;
        float4 v = ((const float4*)x)[i];
        ushort4 o; o.x = f2bf(v.x); o.y = f2bf(v.y); o.z = f2bf(v.z); o.w = f2bf(v.w);
        ((ushort4*)xb)[i] = o;
        return;
    }
    if (bid < nbCast + 64){                  // ---- weight cast (4 x 128x128) ----
        int i = (bid - nbCast) * 256 + threadIdx.x;   // 0..16383 float4s
        int sel = i >> 12, j = i & 4095;
        const float* s = sel == 0 ? a0 : sel == 1 ? a1 : sel == 2 ? a2 : a3;
        ushort*      d = sel == 0 ? o0 : sel == 1 ? o1 : sel == 2 ? o2 : o3;
        float4 v = ((const float4*)s)[j];
        ushort4 o; o.x = f2bf(v.x); o.y = f2bf(v.y); o.z = f2bf(v.z); o.w = f2bf(v.w);
        ((ushort4*)d)[j] = o;
        return;
    }
    // ---- bucket histogram ----
    __shared__ int h[NBUCK];
    h[threadIdx.x] = 0;
    __syncthreads();
    int base = (bid - nbCast - 64) * 4096 + threadIdx.x;
    #pragma unroll
    for (int k = 0; k < 16; k++){
        int e = base + k * 256;
        if (e < E) atomicAdd(&h[dst[e] >> BSHIFT], 1);
    }
    __syncthreads();
    int c = h[threadIdx.x];
    if (c) atomicAdd(&bcnt[threadIdx.x], c);
}

// ================= CSR build via bucket counting-sort =================
// Also zeroes the pooled accumulator (saves a memset launch).
__global__ void k_bscan(const int* __restrict__ bcnt, int* __restrict__ bbase,
                        int* __restrict__ bpos, int* __restrict__ rowp,
                        int* __restrict__ csr, float* __restrict__ pooled,
                        int E, int M){
    __shared__ int sd[NBUCK];
    int t = threadIdx.x;
    #pragma unroll
    for (int k = 0; k < 32; k++) pooled[t * 32 + k] = 0.f;   // 256*32 = 8192
    int v = bcnt[t];
    sd[t] = v; __syncthreads();
    for (int off = 1; off < NBUCK; off <<= 1){
        int x = (t >= off) ? sd[t - off] : 0;
        __syncthreads();
        sd[t] += x;
        __syncthreads();
    }
    int ex = sd[t] - v;
    bbase[t] = ex;
    bpos[t]  = ex;
    if (t < 8) csr[E + t] = 0;                 // zero the read-ahead pad
    if (t == NBUCK - 1){ bbase[NBUCK] = sd[t]; rowp[M] = E; }
}

__global__ __launch_bounds__(256) void k_bucket(const int* __restrict__ src,
                                                const int* __restrict__ dst,
                                                int* __restrict__ bpos,
                                                int2* __restrict__ bp, int E){
    __shared__ int h[NBUCK];
    __shared__ int bb[NBUCK];
    int t = threadIdx.x;
    h[t] = 0;
    __syncthreads();
    int base = blockIdx.x * 4096 + t;
    int bk[16], sv[16], dv[16];
    #pragma unroll
    for (int k = 0; k < 16; k++){
        int e = base + k * 256;
        if (e < E){
            dv[k] = dst[e]; sv[k] = src[e];
            bk[k] = dv[k] >> BSHIFT;
            atomicAdd(&h[bk[k]], 1);
        } else bk[k] = -1;
    }
    __syncthreads();
    int c = h[t];
    bb[t] = c ? atomicAdd(&bpos[t], c) : 0;
    __syncthreads();
    h[t] = 0;
    __syncthreads();
    #pragma unroll
    for (int k = 0; k < 16; k++){
        if (bk[k] >= 0){
            int r = atomicAdd(&h[bk[k]], 1);
            bp[bb[bk[k]] + r] = make_int2(sv[k], dv[k]);
        }
    }
}

__global__ __launch_bounds__(512) void k_csr(const int2* __restrict__ bp,
                                             const int* __restrict__ bbase,
                                             int* __restrict__ rowp,
                                             int* __restrict__ csr, int M){
    __shared__ int cnt[512];
    __shared__ int sd[512];
    int b = blockIdx.x, t = threadIdx.x;
    int nbase = b << BSHIFT;
    int nnodes = min(512, M - nbase);
    int e0 = bbase[b], e1 = bbase[b + 1];
    cnt[t] = 0;
    __syncthreads();
    for (int e = e0 + t; e < e1; e += 512)
        atomicAdd(&cnt[bp[e].y - nbase], 1);
    __syncthreads();
    int v = cnt[t];
    sd[t] = v; __syncthreads();
    for (int off = 1; off < 512; off <<= 1){
        int x = (t >= off) ? sd[t - off] : 0;
        __syncthreads();
        sd[t] += x;
        __syncthreads();
    }
    int ex = sd[t] - v;
    if (t < nnodes) rowp[nbase + t] = e0 + ex;
    cnt[t] = ex;     // running cursor
    __syncthreads();
    for (int e = e0 + t; e < e1; e += 512){
        int2 pr = bp[e];
        int r = atomicAdd(&cnt[pr.y - nbase], 1);
        csr[e0 + r] = pr.x;
    }
}

// ---------------- mean aggregation: 16 lanes/node, 4 nodes/wave, 8-deep ----------------
// At the per-CU VMEM service ceiling (~10 B/cyc/CU) — structural floor for bf16.
#define ACCA(vv)                                   \
    a0 += bf2f_lo((vv).x); a1 += bf2f_hi((vv).x);  \
    a2 += bf2f_lo((vv).y); a3 += bf2f_hi((vv).y);  \
    a4 += bf2f_lo((vv).z); a5 += bf2f_hi((vv).z);  \
    a6 += bf2f_lo((vv).w); a7 += bf2f_hi((vv).w);
#define ACCB(vv)                                   \
    b0 += bf2f_lo((vv).x); b1 += bf2f_hi((vv).x);  \
    b2 += bf2f_lo((vv).y); b3 += bf2f_hi((vv).y);  \
    b4 += bf2f_lo((vv).z); b5 += bf2f_hi((vv).z);  \
    b6 += bf2f_lo((vv).w); b7 += bf2f_hi((vv).w);

__global__ __launch_bounds__(256) void k_agg(const ushort* __restrict__ srcf,
                                             const int* __restrict__ rowp,
                                             const int* __restrict__ csr,
                                             ushort* __restrict__ aggb, int M){
    int node = blockIdx.x * 16 + (threadIdx.x >> 4);
    int l    = threadIdx.x & 15;
    if (node >= M) return;
    int s = rowp[node], e = rowp[node + 1];
    const char* base = (const char*)srcf + (uint)l * 16u;   // this lane's 8 feats
    float a0 = 0.f, a1 = 0.f, a2 = 0.f, a3 = 0.f;
    float a4 = 0.f, a5 = 0.f, a6 = 0.f, a7 = 0.f;
    float b0 = 0.f, b1 = 0.f, b2 = 0.f, b3 = 0.f;
    float b4 = 0.f, b5 = 0.f, b6 = 0.f, b7 = 0.f;
    int i = s;
    for (; i + 8 <= e; i += 8){
        int idx[8];
        __builtin_memcpy(idx, csr + i, 32);        // two group-uniform dwordx4
        uint4 v0 = *(const uint4*)(base + ((uint)idx[0] << 8));
        uint4 v1 = *(const uint4*)(base + ((uint)idx[1] << 8));
        uint4 v2 = *(const uint4*)(base + ((uint)idx[2] << 8));
        uint4 v3 = *(const uint4*)(base + ((uint)idx[3] << 8));
        uint4 v4 = *(const uint4*)(base + ((uint)idx[4] << 8));
        uint4 v5 = *(const uint4*)(base + ((uint)idx[5] << 8));
        uint4 v6 = *(const uint4*)(base + ((uint)idx[6] << 8));
        uint4 v7 = *(const uint4*)(base + ((uint)idx[7] << 8));
        ACCA(v0); ACCA(v1); ACCA(v2); ACCA(v3);
        ACCB(v4); ACCB(v5); ACCB(v6); ACCB(v7);
    }
    if (i + 4 <= e){
        int idx[4];
        __builtin_memcpy(idx, csr + i, 16);
        uint4 v0 = *(const uint4*)(base + ((uint)idx[0] << 8));
        uint4 v1 = *(const uint4*)(base + ((uint)idx[1] << 8));
        uint4 v2 = *(const uint4*)(base + ((uint)idx[2] << 8));
        uint4 v3 = *(const uint4*)(base + ((uint)idx[3] << 8));
        ACCA(v0); ACCA(v1); ACCB(v2); ACCB(v3);
        i += 4;
    }
    for (; i < e; i++){                            // <=3 tail edges
        uint4 v = *(const uint4*)(base + ((uint)csr[i] << 8));
        ACCA(v);
    }
    float inv = (e > s) ? 1.0f / (float)(e - s) : 0.f;  // count clamped to 1
    uint4 o;
    o.x = ((uint)f2bf((a1 + b1) * inv) << 16) | (uint)f2bf((a0 + b0) * inv);
    o.y = ((uint)f2bf((a3 + b3) * inv) << 16) | (uint)f2bf((a2 + b2) * inv);
    o.z = ((uint)f2bf((a5 + b5) * inv) << 16) | (uint)f2bf((a4 + b4) * inv);
    o.w = ((uint)f2bf((a7 + b7) * inv) << 16) | (uint)f2bf((a6 + b6) * inv);
    *(uint4*)(aggb + (size_t)node * FEAT + l * 8) = o;
}

// ---------------- fused SAGE linear: H = relu(AGG@Wl^T + b + A@Wr^T) ----------------
// 128-row tiles, 512 threads (8 waves x 16 rows). W staged in LDS; A-fragments
// direct from global. mode 0: store H (layer 1). mode 1 (layer 2): fuse graph
// sum-pooling. Atomic-storm-safe: graph-uniform blocks (~90%) reduce through
// LDS first -> 128 global atomics/block. No threadfence, no last-block pattern.
__global__ __launch_bounds__(512) void k_gemm(
    const ushort* __restrict__ Aagg, const ushort* __restrict__ Aself,
    const ushort* __restrict__ Wl, const ushort* __restrict__ Wr,
    const float* __restrict__ bias, ushort* __restrict__ Hout, int M, int mode,
    float* __restrict__ pooled, const int* __restrict__ batch)
{
    __shared__ ushort Bs[128 * LDA];
    const int tid  = threadIdx.x;
    const int lane = tid & 63;
    const int wave = tid >> 6;          // 0..7
    const int l15  = lane & 15;
    const int quad = lane >> 4;
    const int m0   = blockIdx.x * 128;

    int arow = m0 + wave * 16 + l15;
    if (arow >= M) arow = M - 1;        // clamped; junk only corrupts masked rows
    const ushort* ap0 = Aagg  + (size_t)arow * FEAT + quad * 8;
    const ushort* ap1 = Aself + (size_t)arow * FEAT + quad * 8;

    f4_t acc[8];
    #pragma unroll
    for (int i = 0; i < 8; i++) acc[i] = (f4_t){0.f, 0.f, 0.f, 0.f};

    #pragma unroll
    for (int pass = 0; pass < 2; pass++){
        const ushort* Ap = pass ? ap1 : ap0;
        const ushort* Wp = pass ? Wr  : Wl;
        #pragma unroll
        for (int it = 0; it < 4; it++){          // 2048 int4 / 512 thr
            int idx = (it * 512 + tid) * 8;
            int r = idx >> 7, c = idx & 127;
            *(int4*)(&Bs[r * LDA + c]) = *(const int4*)(Wp + idx);
        }
        bf8_t ga0 = *(const bf8_t*)(Ap);
        bf8_t ga1 = *(const bf8_t*)(Ap + 32);
        bf8_t ga2 = *(const bf8_t*)(Ap + 64);
        bf8_t ga3 = *(const bf8_t*)(Ap + 96);
        __syncthreads();
        const ushort* brow = &Bs[l15 * LDA + quad * 8];
        #pragma unroll
        for (int nt = 0; nt < 8; nt++){
            const ushort* b = brow + nt * 16 * LDA;
            acc[nt] = __builtin_amdgcn_mfma_f32_16x16x32_bf16(ga0, *(const bf8_t*)(b),      acc[nt], 0, 0, 0);
            acc[nt] = __builtin_amdgcn_mfma_f32_16x16x32_bf16(ga1, *(const bf8_t*)(b + 32), acc[nt], 0, 0, 0);
            acc[nt] = __builtin_amdgcn_mfma_f32_16x16x32_bf16(ga2, *(const bf8_t*)(b + 64), acc[nt], 0, 0, 0);
            acc[nt] = __builtin_amdgcn_mfma_f32_16x16x32_bf16(ga3, *(const bf8_t*)(b + 96), acc[nt], 0, 0, 0);
        }
        __syncthreads();
    }

    if (mode == 0){
        // ---- layer-1 epilogue: bias + relu -> bf16 store ----
        #pragma unroll
        for (int nt = 0; nt < 8; nt++){
            int col = nt * 16 + l15;
            float bcol = bias[col];
            #pragma unroll
            for (int reg = 0; reg < 4; reg++){
                int gm = m0 + wave * 16 + quad * 4 + reg;
                if (gm < M){
                    float v = acc[nt][reg] + bcol;
                    v = v > 0.f ? v : 0.f;
                    Hout[(size_t)gm * FEAT + col] = f2bf(v);
                }
            }
        }
        return;
    }

    // ---- layer-2 epilogue: fused graph sum-pool (sorted batch) ----
    // Bs is dead after the final barrier of the MFMA loop -> reuse as f32 scratch.
    float* ps = (float*)Bs;                            // [8 waves][128 cols]
    int gfirst = batch[m0];
    int glast  = batch[min(m0 + 127, M - 1)];
    if (m0 + 128 <= M && gfirst == glast){
        // fast path: whole block one graph. Quad-reduce -> LDS -> 128 atomics/block.
        #pragma unroll
        for (int nt = 0; nt < 8; nt++){
            float bcol = bias[nt * 16 + l15];
            float v = 0.f;
            #pragma unroll
            for (int reg = 0; reg < 4; reg++){
                float t = acc[nt][reg] + bcol;
                v += t > 0.f ? t : 0.f;
            }
            v += __shfl_xor(v, 16);
            v += __shfl_xor(v, 32);
            if (lane < 16) ps[wave * FEAT + nt * 16 + l15] = v;
        }
        __syncthreads();
        if (tid < FEAT){
            float s = 0.f;
            #pragma unroll
            for (int w8 = 0; w8 < 8; w8++) s += ps[w8 * FEAT + tid];
            atomicAdd(&pooled[gfirst * FEAT + tid], s);
        }
        return;
    }
    // slow path (block spans graphs, or tail): per-16-row-window handling
    {
        int row0 = m0 + wave * 16 + quad * 4;          // this lane's 4 rows
        bool wfull = (m0 + wave * 16 + 16 <= M);       // wave's 16-row window valid
        if (wfull){
            int4 gq = *(const int4*)(batch + row0);
            int g_lo = __shfl(gq.x, 0);                // row wave*16 + 0
            int g_hi = __shfl(gq.w, 48);               // row wave*16 + 15
            if (g_lo == g_hi){
                #pragma unroll
                for (int nt = 0; nt < 8; nt++){
                    float bcol = bias[nt * 16 + l15];
                    float v = 0.f;
                    #pragma unroll
                    for (int reg = 0; reg < 4; reg++){
                        float t = acc[nt][reg] + bcol;
                        v += t > 0.f ? t : 0.f;
                    }
                    v += __shfl_xor(v, 16);
                    v += __shfl_xor(v, 32);
                    if (lane < 16)
                        atomicAdd(&pooled[g_lo * FEAT + nt * 16 + l15], v);
                }
            } else {
                // window spans graphs: run-length per lane
                #pragma unroll
                for (int nt = 0; nt < 8; nt++){
                    int col = nt * 16 + l15;
                    float bcol = bias[col];
                    float s = 0.f; int g = gq.x;
                    #pragma unroll
                    for (int reg = 0; reg < 4; reg++){
                        int gn = reg == 0 ? gq.x : reg == 1 ? gq.y : reg == 2 ? gq.z : gq.w;
                        float t = acc[nt][reg] + bcol;
                        t = t > 0.f ? t : 0.f;
                        if (gn != g){ atomicAdd(&pooled[g * FEAT + col], s); s = 0.f; g = gn; }
                        s += t;
                    }
                    atomicAdd(&pooled[g * FEAT + col], s);
                }
            }
        } else if (row0 < M){
            // partial window: per-row guarded atomics (rare tail)
            #pragma unroll
            for (int nt = 0; nt < 8; nt++){
                int col = nt * 16 + l15;
                float bcol = bias[col];
                #pragma unroll
                for (int reg = 0; reg < 4; reg++){
                    int gm = row0 + reg;
                    if (gm < M){
                        float t = acc[nt][reg] + bcol;
                        t = t > 0.f ? t : 0.f;
                        atomicAdd(&pooled[batch[gm] * FEAT + col], t);
                    }
                }
            }
        }
    }
}

// ---------------- final linear over [pooled/cnt | embed] ----------------
__global__ void k_final(const float* __restrict__ pooled, const int* __restrict__ batch,
                        const float* __restrict__ embed, const float* __restrict__ Wlin,
                        const float* __restrict__ blin, float* __restrict__ out, int M){
    int t = threadIdx.x;
    if (t >= GR * 8) return;
    int g = t >> 3, o = t & 7;
    int lo = 0, hi = M;
    while (lo < hi){ int mid = (lo + hi) >> 1; if (batch[mid] < g) lo = mid + 1; else hi = mid; }
    int s0 = lo;
    lo = s0; hi = M;
    while (lo < hi){ int mid = (lo + hi) >> 1; if (batch[mid] < g + 1) lo = mid + 1; else hi = mid; }
    int c = lo - s0;
    float inv = (c > 0) ? 1.0f / (float)c : 0.f;
    float acc = blin[o];
    const float* wr = Wlin + o * (FEAT + GR);
    for (int k = 0; k < FEAT; k++) acc += pooled[g * FEAT + k] * inv * wr[k];
    for (int k = 0; k < GR; k++)   acc += embed[g * GR + k] * wr[FEAT + k];
    out[g * 8 + o] = acc;
}

extern "C" void kernel_launch(void* const* d_in, const int* in_sizes, int n_in,
                              void* d_out, int out_size, void* d_ws, size_t ws_size,
                              hipStream_t stream)
{
    const float* x     = (const float*)d_in[0];
    const int*   eidx  = (const int*)d_in[1];
    const int*   batch = (const int*)d_in[2];
    const float* embed = (const float*)d_in[3];
    const float* W1l   = (const float*)d_in[4];
    const float* b1l   = (const float*)d_in[5];
    const float* W1r   = (const float*)d_in[6];
    const float* W2l   = (const float*)d_in[7];
    const float* b2l   = (const float*)d_in[8];
    const float* W2r   = (const float*)d_in[9];
    const float* Wlin  = (const float*)d_in[10];
    const float* blin  = (const float*)d_in[11];
    float* out = (float*)d_out;

    const int M = in_sizes[0] / FEAT;   // 100000
    const int E = in_sizes[1] / 2;      // 800000
    const int* src = eidx;
    const int* dst = eidx + E;

    char* w = (char*)d_ws;
    size_t off = 0;
    auto alloc = [&](size_t sz){ void* p = w + off; off = (off + sz + 255) & ~(size_t)255; return p; };
    ushort* xb     = (ushort*)alloc((size_t)M * FEAT * 2);
    ushort* aggb   = (ushort*)alloc((size_t)M * FEAT * 2);
    ushort* h1b    = (ushort*)alloc((size_t)M * FEAT * 2);
    int*    rowp   = (int*)alloc((size_t)(M + 1) * 4);
    int*    csr    = (int*)alloc((size_t)(E + 8) * 4);   // +8 read-ahead pad
    int*    bcnt   = (int*)alloc(NBUCK * 4);
    int*    bbase  = (int*)alloc((NBUCK + 1) * 4);
    int*    bpos   = (int*)alloc(NBUCK * 4);
    float*  pooled = (float*)alloc((size_t)GR * FEAT * 4);
    ushort* w1lb   = (ushort*)alloc((size_t)FEAT * FEAT * 2);
    ushort* w1rb   = (ushort*)alloc((size_t)FEAT * FEAT * 2);
    ushort* w2lb   = (ushort*)alloc((size_t)FEAT * FEAT * 2);
    ushort* w2rb   = (ushort*)alloc((size_t)FEAT * FEAT * 2);
    int2*   bp     = (int2*)aggb;   // bucket-sorted pairs; dead before aggb first written

    hipMemsetAsync(bcnt, 0, NBUCK * 4, stream);

    const int n4     = M * FEAT / 4;
    const int nbCast = (n4 + 255) / 256;
    const int nb     = (M + 511) >> BSHIFT;     // buckets actually populated
    const int ebk    = (E + 4095) / 4096;       // edge-chunk blocks
    const int gemmb  = (M + 127) / 128;
    k_prep  <<<nbCast + 64 + ebk, 256, 0, stream>>>(x, xb, n4, nbCast,
                                                    W1l, W1r, W2l, W2r,
                                                    w1lb, w1rb, w2lb, w2rb,
                                                    dst, bcnt, E);
    k_bscan <<<1, NBUCK, 0, stream>>>(bcnt, bbase, bpos, rowp, csr, pooled, E, M);
    k_bucket<<<ebk, 256, 0, stream>>>(src, dst, bpos, bp, E);
    k_csr   <<<nb, 512, 0, stream>>>(bp, bbase, rowp, csr, M);
    k_agg   <<<(M + 15) / 16, 256, 0, stream>>>(xb, rowp, csr, aggb, M);
    k_gemm  <<<gemmb, 512, 0, stream>>>(aggb, xb, w1lb, w1rb, b1l, h1b, M, 0,
                                        nullptr, nullptr);
    k_agg   <<<(M + 15) / 16, 256, 0, stream>>>(h1b, rowp, csr, aggb, M);
    k_gemm  <<<gemmb, 512, 0, stream>>>(aggb, h1b, w2lb, w2rb, b2l, nullptr, M, 1,
                                        pooled, batch);
    k_final <<<1, 512, 0, stream>>>(pooled, batch, embed, Wlin, blin, out, M);
}